// Round 2
// baseline (255.715 us; speedup 1.0000x reference)
//
#include <hip/hip_runtime.h>

// One step of the c4-style VM.
// Outputs (int32, concatenated): [pc, sp, bp, ax, memory(33554432), halted]
// ws layout (int32): ws[0]=layout flag (0=int32,1=int64-LE,2=float32),
//                    ws[1]=n byte-writes, ws[2+2k]=mem index, ws[3+2k]=byte value

static constexpr long long MEMN = 33554432LL;

__device__ __forceinline__ long long clamp_idx(long long a) {
    return a < 0 ? 0 : (a > MEMN - 1 ? MEMN - 1 : a);
}

__device__ __forceinline__ long long rd_byte(const void* mem, int flag, long long idx) {
    long long j = clamp_idx(idx);
    if (flag == 2) return (long long)((const float*)mem)[j];
    if (flag == 1) return (long long)((const int*)mem)[j << 1];  // low word of LE int64
    return (long long)((const int*)mem)[j];
}

__device__ __forceinline__ long long rd_int(const void* mem, int flag, long long addr) {
    unsigned long long v = 0;
    #pragma unroll
    for (int k = 0; k < 8; ++k)
        v |= (unsigned long long)(unsigned int)rd_byte(mem, flag, addr + k) << (8 * k);
    return (long long)v;
}

__device__ __forceinline__ long long rd_scalar(const void* p, int flag) {
    if (flag == 2) return (long long)((const float*)p)[0];
    return (long long)((const int*)p)[0];  // low word: correct for int32 and small LE int64
}

__global__ void vm_step(const void* pc_b, const void* sp_b, const void* bp_b,
                        const void* ax_b, const void* mem_b, int* out, int* ws) {
    if (threadIdx.x != 0 || blockIdx.x != 0) return;

    // ---- classify memory buffer layout ----
    const int* mi = (const int*)mem_b;
    int flag;
    {
        bool big = false;
        bool odd_zero = true;
        for (int i = 0; i < 64; ++i) {
            unsigned int w = (unsigned int)mi[i];
            if (w > 255u) big = true;
            if ((i & 1) && w != 0u) odd_zero = false;
        }
        flag = big ? 2 : (odd_zero ? 1 : 0);
    }
    ws[0] = flag;

    long long pc = rd_scalar(pc_b, flag);
    long long sp = rd_scalar(sp_b, flag);
    long long bp = rd_scalar(bp_b, flag);
    long long ax = rd_scalar(ax_b, flag);

    // ---- fetch / decode / loads ----
    long long ins       = rd_int(mem_b, flag, pc);
    long long opcode    = ins & 255;
    long long imm       = ins >> 8;               // arithmetic
    long long stack_top = rd_int(mem_b, flag, sp);
    long long mem_at_ax = rd_int(mem_b, flag, ax);
    long long ret_pc    = rd_int(mem_b, flag, bp + 8);
    long long bp_stack  = rd_int(mem_b, flag, bp);
    long long pc8       = (long long)((unsigned long long)pc + 8ULL);

    // ---- ALU helpers (wrap-safe, Python floor-div/mod semantics) ----
    unsigned long long ust = (unsigned long long)stack_top;
    unsigned long long uax = (unsigned long long)ax;
    long long ax_safe = (ax == 0) ? 1LL : ax;
    long long q, r;
    if (ax_safe == -1LL) { q = (long long)(0ULL - ust); r = 0; }
    else {
        q = stack_top / ax_safe; r = stack_top % ax_safe;
        if (r != 0 && ((r < 0) != (ax_safe < 0))) { q -= 1; r += ax_safe; }
    }
    int sh = (int)(ax & 63);

    long long op = opcode > 38 ? 38 : opcode;
    long long npc = pc8, nsp = sp, nbp = bp, nax = ax;
    switch ((int)op) {
        case 0:  nax = (long long)((unsigned long long)bp + (unsigned long long)imm); break; // LEA
        case 1:  nax = imm; break;                                                           // IMM
        case 2:  npc = imm; break;                                                           // JMP
        case 3:  npc = imm; nsp = sp - 8; break;                                             // JSR
        case 4:  npc = (ax == 0) ? imm : pc8; break;                                         // BZ
        case 5:  npc = (ax != 0) ? imm : pc8; break;                                         // BNZ
        case 6:  nsp = sp - 8 - imm; nbp = sp - 8; break;                                    // ENT
        case 7:  nsp = sp + imm; break;                                                      // ADJ
        case 8:  npc = ret_pc; nsp = bp + 16; nbp = bp_stack; break;                         // LEV
        case 9:  nax = mem_at_ax; break;                                                     // LI
        case 10: nax = mem_at_ax & 255; break;                                               // LC
        case 11: nsp = sp + 8; break;                                                        // SI
        case 12: nsp = sp + 8; break;                                                        // SC
        case 13: nsp = sp - 8; break;                                                        // PSH
        case 14: nsp = sp + 8; nax = (long long)(ust + uax); break;
        case 15: nsp = sp + 8; nax = (long long)(ust - uax); break;
        case 16: nsp = sp + 8; nax = (long long)(ust * uax); break;
        case 17: nsp = sp + 8; nax = q; break;
        case 18: nsp = sp + 8; nax = r; break;
        case 19: nsp = sp + 8; nax = stack_top | ax; break;
        case 20: nsp = sp + 8; nax = stack_top ^ ax; break;
        case 21: nsp = sp + 8; nax = stack_top & ax; break;
        case 22: nsp = sp + 8; nax = (long long)(ust << sh); break;
        case 23: nsp = sp + 8; nax = stack_top >> sh; break;   // arithmetic
        case 24: nsp = sp + 8; nax = (stack_top == ax) ? 1 : 0; break;
        case 25: nsp = sp + 8; nax = (stack_top != ax) ? 1 : 0; break;
        case 26: nsp = sp + 8; nax = (stack_top <  ax) ? 1 : 0; break;
        case 27: nsp = sp + 8; nax = (stack_top >  ax) ? 1 : 0; break;
        case 28: nsp = sp + 8; nax = (stack_top <= ax) ? 1 : 0; break;
        case 29: nsp = sp + 8; nax = (stack_top >= ax) ? 1 : 0; break;
        case 38: npc = pc; break;                                                            // EXIT
        default: nax = 0; break;                                                             // 30..37
    }

    out[0] = (int)npc;
    out[1] = (int)nsp;
    out[2] = (int)nbp;
    out[3] = (int)nax;
    out[4 + MEMN] = (opcode == 38) ? 1 : 0;

    // ---- byte-write descriptors (at most one store op fires) ----
    int nw = 0;
    long long waddr = 0; unsigned long long wval = 0; int wbytes = 0;
    if (opcode == 13 || opcode == 3 || opcode == 6) {       // PSH / JSR / ENT push
        waddr = sp - 8;
        wval = (unsigned long long)(opcode == 13 ? ax : (opcode == 3 ? pc8 : bp));
        wbytes = 8;
    } else if (opcode == 11) {                              // SI
        waddr = stack_top; wval = (unsigned long long)ax; wbytes = 8;
    } else if (opcode == 12) {                              // SC
        waddr = stack_top; wval = (unsigned long long)(ax & 255); wbytes = 1;
    }
    for (int k = 0; k < wbytes; ++k) {
        long long j = clamp_idx(waddr + k);
        ws[2 + 2 * nw] = (int)j;
        ws[3 + 2 * nw] = (int)((wval >> (8 * k)) & 255ULL);
        ++nw;
    }
    ws[1] = nw;
}

__global__ void copy_mem(const void* mem_b, int* out, const int* ws) {
    int flag = ws[0];
    long long tid    = (long long)blockIdx.x * blockDim.x + threadIdx.x;
    long long stride = (long long)gridDim.x * blockDim.x;
    const long long nvec = MEMN / 4;
    int4* o = (int4*)(out + 4);   // out+4 is 16B-aligned
    if (flag == 1) {
        const int4* m = (const int4*)mem_b;
        for (long long i = tid; i < nvec; i += stride) {
            int4 a = m[2 * i];
            int4 b = m[2 * i + 1];
            int4 f; f.x = a.x; f.y = a.z; f.z = b.x; f.w = b.z;
            o[i] = f;
        }
    } else if (flag == 0) {
        const int4* m = (const int4*)mem_b;
        for (long long i = tid; i < nvec; i += stride) o[i] = m[i];
    } else {
        const float4* m = (const float4*)mem_b;
        for (long long i = tid; i < nvec; i += stride) {
            float4 v = m[i];
            int4 f; f.x = (int)v.x; f.y = (int)v.y; f.z = (int)v.z; f.w = (int)v.w;
            o[i] = f;
        }
    }
}

__global__ void apply_writes(int* out, const int* ws) {
    if (threadIdx.x != 0 || blockIdx.x != 0) return;
    int n = ws[1];
    for (int k = 0; k < n; ++k)
        out[4 + ws[2 + 2 * k]] = ws[3 + 2 * k];   // sequential: last-wins
}

extern "C" void kernel_launch(void* const* d_in, const int* in_sizes, int n_in,
                              void* d_out, int out_size, void* d_ws, size_t ws_size,
                              hipStream_t stream) {
    int* out = (int*)d_out;
    int* ws = (int*)d_ws;
    vm_step<<<1, 64, 0, stream>>>(d_in[0], d_in[1], d_in[2], d_in[3], d_in[4], out, ws);
    copy_mem<<<2048, 256, 0, stream>>>(d_in[4], out, ws);
    apply_writes<<<1, 64, 0, stream>>>(out, ws);
}

// Round 5
// 250.332 us; speedup vs baseline: 1.0215x; 1.0215x over previous
//
#include <hip/hip_runtime.h>

// One step of the c4-style VM, fully fused into a single kernel.
// Outputs (int32, concatenated): [pc, sp, bp, ax, memory(33554432), halted]
//
// Every block: wave 0 classifies the input layout (int32 / int64-LE / float32)
// with one parallel load + ballot; lane 0 replays the scalar VM step (L2-hot
// after block 0) and posts <=8 patched (index,byte) pairs to LDS. All threads
// then stream-copy memory -> out, substituting patched bytes inline.

static constexpr long long MEMN = 33554432LL;
static constexpr int NT = 256;
static constexpr int NB = 4096;
static constexpr int ITERS = 8;   // NB*NT*ITERS == MEMN/4 (int4 chunks)

__device__ __forceinline__ long long clamp_idx(long long a) {
    return a < 0 ? 0 : (a > MEMN - 1 ? MEMN - 1 : a);
}

__device__ __forceinline__ long long rd_byte(const void* mem, int flag, long long idx) {
    long long j = clamp_idx(idx);
    if (flag == 2) return (long long)((const float*)mem)[j];
    if (flag == 1) return (long long)((const int*)mem)[j << 1];  // low word of LE int64
    return (long long)((const int*)mem)[j];
}

__device__ __forceinline__ long long rd_int(const void* mem, int flag, long long addr) {
    unsigned long long v = 0;
    #pragma unroll
    for (int k = 0; k < 8; ++k)
        v |= (unsigned long long)(unsigned int)rd_byte(mem, flag, addr + k) << (8 * k);
    return (long long)v;
}

__device__ __forceinline__ long long rd_scalar(const void* p, int flag) {
    if (flag == 2) return (long long)((const float*)p)[0];
    return (long long)((const int*)p)[0];  // low word: ok for int32 and small LE int64
}

__global__ __launch_bounds__(NT) void fused_step(const void* pc_b, const void* sp_b,
                                                 const void* bp_b, const void* ax_b,
                                                 const void* mem_b, int* out) {
    __shared__ int s_flag, s_nw, s_lo, s_hi;
    __shared__ int s_idx[8], s_val[8];

    const int* mi = (const int*)mem_b;

    // ---- wave 0: classify layout; lane 0: VM step ----
    if (threadIdx.x < 64) {
        unsigned int w = (unsigned int)mi[threadIdx.x];
        unsigned long long big    = __ballot(w > 255u);
        unsigned long long oddnz  = __ballot(((threadIdx.x & 1) != 0) && (w != 0u));
        if (threadIdx.x == 0) {
            int flag = big ? 2 : (oddnz ? 0 : 1);
            s_flag = flag;

            long long pc = rd_scalar(pc_b, flag);
            long long sp = rd_scalar(sp_b, flag);
            long long bp = rd_scalar(bp_b, flag);
            long long ax = rd_scalar(ax_b, flag);

            long long ins       = rd_int(mem_b, flag, pc);
            long long opcode    = ins & 255;
            long long imm       = ins >> 8;
            long long stack_top = rd_int(mem_b, flag, sp);
            long long mem_at_ax = rd_int(mem_b, flag, ax);
            long long ret_pc    = rd_int(mem_b, flag, bp + 8);
            long long bp_stack  = rd_int(mem_b, flag, bp);
            long long pc8       = (long long)((unsigned long long)pc + 8ULL);

            unsigned long long ust = (unsigned long long)stack_top;
            unsigned long long uax = (unsigned long long)ax;
            long long ax_safe = (ax == 0) ? 1LL : ax;
            long long q, r;
            if (ax_safe == -1LL) { q = (long long)(0ULL - ust); r = 0; }
            else {
                q = stack_top / ax_safe; r = stack_top % ax_safe;
                if (r != 0 && ((r < 0) != (ax_safe < 0))) { q -= 1; r += ax_safe; }
            }
            int sh = (int)(ax & 63);

            long long op = opcode > 38 ? 38 : opcode;
            long long npc = pc8, nsp = sp, nbp = bp, nax = ax;
            switch ((int)op) {
                case 0:  nax = (long long)((unsigned long long)bp + (unsigned long long)imm); break;
                case 1:  nax = imm; break;
                case 2:  npc = imm; break;
                case 3:  npc = imm; nsp = sp - 8; break;
                case 4:  npc = (ax == 0) ? imm : pc8; break;
                case 5:  npc = (ax != 0) ? imm : pc8; break;
                case 6:  nsp = sp - 8 - imm; nbp = sp - 8; break;
                case 7:  nsp = sp + imm; break;
                case 8:  npc = ret_pc; nsp = bp + 16; nbp = bp_stack; break;
                case 9:  nax = mem_at_ax; break;
                case 10: nax = mem_at_ax & 255; break;
                case 11: nsp = sp + 8; break;
                case 12: nsp = sp + 8; break;
                case 13: nsp = sp - 8; break;
                case 14: nsp = sp + 8; nax = (long long)(ust + uax); break;
                case 15: nsp = sp + 8; nax = (long long)(ust - uax); break;
                case 16: nsp = sp + 8; nax = (long long)(ust * uax); break;
                case 17: nsp = sp + 8; nax = q; break;
                case 18: nsp = sp + 8; nax = r; break;
                case 19: nsp = sp + 8; nax = stack_top | ax; break;
                case 20: nsp = sp + 8; nax = stack_top ^ ax; break;
                case 21: nsp = sp + 8; nax = stack_top & ax; break;
                case 22: nsp = sp + 8; nax = (long long)(ust << sh); break;
                case 23: nsp = sp + 8; nax = stack_top >> sh; break;
                case 24: nsp = sp + 8; nax = (stack_top == ax) ? 1 : 0; break;
                case 25: nsp = sp + 8; nax = (stack_top != ax) ? 1 : 0; break;
                case 26: nsp = sp + 8; nax = (stack_top <  ax) ? 1 : 0; break;
                case 27: nsp = sp + 8; nax = (stack_top >  ax) ? 1 : 0; break;
                case 28: nsp = sp + 8; nax = (stack_top <= ax) ? 1 : 0; break;
                case 29: nsp = sp + 8; nax = (stack_top >= ax) ? 1 : 0; break;
                case 38: npc = pc; break;
                default: nax = 0; break;
            }

            // byte-write descriptors (opcodes are mutually exclusive -> one range)
            int nw = 0, lo = 0x7fffffff, hi = -1;
            long long waddr = 0; unsigned long long wval = 0; int wbytes = 0;
            if (opcode == 13 || opcode == 3 || opcode == 6) {
                waddr = sp - 8;
                wval = (unsigned long long)(opcode == 13 ? ax : (opcode == 3 ? pc8 : bp));
                wbytes = 8;
            } else if (opcode == 11) {
                waddr = stack_top; wval = (unsigned long long)ax; wbytes = 8;
            } else if (opcode == 12) {
                waddr = stack_top; wval = (unsigned long long)(ax & 255); wbytes = 1;
            }
            for (int k = 0; k < wbytes; ++k) {
                int j = (int)clamp_idx(waddr + k);
                s_idx[nw] = j;
                s_val[nw] = (int)((wval >> (8 * k)) & 255ULL);
                lo = j < lo ? j : lo;
                hi = j > hi ? j : hi;
                ++nw;
            }
            s_nw = nw; s_lo = lo; s_hi = hi;

            if (blockIdx.x == 0) {
                out[0] = (int)npc;
                out[1] = (int)nsp;
                out[2] = (int)nbp;
                out[3] = (int)nax;
                out[4 + MEMN] = (opcode == 38) ? 1 : 0;
            }
        }
    }
    __syncthreads();

    const int  flag = s_flag;
    const int  nw   = s_nw;
    const int  lo   = s_lo;
    const int  hi   = s_hi;
    const long long tid = (long long)blockIdx.x * NT + threadIdx.x;
    const long long TOT = (long long)NB * NT;
    int4* o = (int4*)(out + 4);   // 16B-aligned

    if (flag == 1) {
        const int4* m = (const int4*)mem_b;
        #pragma unroll
        for (int k = 0; k < ITERS; ++k) {
            long long i = tid + (long long)k * TOT;
            int4 a = m[2 * i];
            int4 b = m[2 * i + 1];
            int4 f; f.x = a.x; f.y = a.z; f.z = b.x; f.w = b.z;
            if (nw) {
                int base = (int)(i << 2);
                if (base + 3 >= lo && base <= hi) {
                    int vals[4] = { f.x, f.y, f.z, f.w };
                    #pragma unroll
                    for (int e = 0; e < 4; ++e)
                        for (int t = 0; t < nw; ++t)
                            if (s_idx[t] == base + e) vals[e] = s_val[t];
                    f.x = vals[0]; f.y = vals[1]; f.z = vals[2]; f.w = vals[3];
                }
            }
            o[i] = f;
        }
    } else if (flag == 0) {
        const int4* m = (const int4*)mem_b;
        #pragma unroll
        for (int k = 0; k < ITERS; ++k) {
            long long i = tid + (long long)k * TOT;
            int4 f = m[i];
            if (nw) {
                int base = (int)(i << 2);
                if (base + 3 >= lo && base <= hi) {
                    int vals[4] = { f.x, f.y, f.z, f.w };
                    #pragma unroll
                    for (int e = 0; e < 4; ++e)
                        for (int t = 0; t < nw; ++t)
                            if (s_idx[t] == base + e) vals[e] = s_val[t];
                    f.x = vals[0]; f.y = vals[1]; f.z = vals[2]; f.w = vals[3];
                }
            }
            o[i] = f;
        }
    } else {
        const float4* m = (const float4*)mem_b;
        #pragma unroll
        for (int k = 0; k < ITERS; ++k) {
            long long i = tid + (long long)k * TOT;
            float4 v = m[i];
            int4 f; f.x = (int)v.x; f.y = (int)v.y; f.z = (int)v.z; f.w = (int)v.w;
            if (nw) {
                int base = (int)(i << 2);
                if (base + 3 >= lo && base <= hi) {
                    int vals[4] = { f.x, f.y, f.z, f.w };
                    #pragma unroll
                    for (int e = 0; e < 4; ++e)
                        for (int t = 0; t < nw; ++t)
                            if (s_idx[t] == base + e) vals[e] = s_val[t];
                    f.x = vals[0]; f.y = vals[1]; f.z = vals[2]; f.w = vals[3];
                }
            }
            o[i] = f;
        }
    }
}

extern "C" void kernel_launch(void* const* d_in, const int* in_sizes, int n_in,
                              void* d_out, int out_size, void* d_ws, size_t ws_size,
                              hipStream_t stream) {
    int* out = (int*)d_out;
    fused_step<<<NB, NT, 0, stream>>>(d_in[0], d_in[1], d_in[2], d_in[3], d_in[4], out);
}